// Round 13
// baseline (89.012 us; speedup 1.0000x reference)
//
#include <hip/hip_runtime.h>
#include <hip/hip_bf16.h>
#include <stdint.h>

// Problem constants
#define B_ 64
#define T_ 512
#define D_ 512
#define H_ 1024
#define M_ (B_*T_)   // 32768
#define K_ D_        // 512
#define N_ H_        // 1024

// Fused-kernel tile: 128 t-rows x 64 h-cols per block (1024 blocks = 4/CU).
#define BM 128
#define BNF 64
#define BK 64
#define NKT (K_/BK)  // 8

// Fallback GEMM tile
#define BN 128

#define L2E 1.44269504f

typedef __attribute__((ext_vector_type(4))) float f32x4;
typedef __attribute__((ext_vector_type(8))) short s16x8;
typedef __attribute__((ext_vector_type(4))) short s16x4;
typedef unsigned short u16;

__device__ __forceinline__ short f2bf(float f) {
  __bf16 h = (__bf16)f;
  return __builtin_bit_cast(short, h);
}
__device__ __forceinline__ float bf2f(u16 u) {
  return __builtin_bit_cast(float, ((unsigned)u) << 16);
}
__device__ __forceinline__ s16x4 cvt4(f32x4 v) {
  s16x4 r;
  r[0] = f2bf(v[0]); r[1] = f2bf(v[1]);
  r[2] = f2bf(v[2]); r[3] = f2bf(v[3]);
  return r;
}
__device__ __forceinline__ void gload_lds16(const void* g, void* l) {
  __builtin_amdgcn_global_load_lds(
      (const __attribute__((address_space(1))) void*)g,
      (__attribute__((address_space(3))) void*)l, 16, 0, 0);
}

// ---------------------------------------------------------------------------
// FAST PATH (needs 1 MB workspace): prep_w (W transpose only) + fused
// ---------------------------------------------------------------------------

// W [K][N] fp32 -> wt [N][K] bf16 via 64x64 LDS tile transpose. 128 blocks.
__global__ __launch_bounds__(256)
void prep_w(const float* __restrict__ W, u16* __restrict__ wt) {
  __shared__ u16 Lt[64 * 72];   // 72-pad keeps 16B alignment of rows
  const int n0 = ((int)blockIdx.x & 15) * 64;
  const int k0 = ((int)blockIdx.x >> 4) * 64;
  const int tid = threadIdx.x;
  #pragma unroll
  for (int p = 0; p < 16; ++p) {
    const int idx = p * 256 + tid;
    const int r = idx >> 6;
    const int c = idx & 63;
    const float v = W[(size_t)(k0 + r) * H_ + n0 + c];
    Lt[c * 72 + r] = (u16)f2bf(v);
  }
  __syncthreads();
  #pragma unroll
  for (int p = 0; p < 2; ++p) {
    const int idx = p * 256 + tid;
    const int rn = idx >> 3;
    const int ck = (idx & 7) * 8;
    const s16x8 v = *(const s16x8*)&Lt[rn * 72 + ck];
    *(s16x8*)&wt[(size_t)(n0 + rn) * K_ + k0 + ck] = v;
  }
}

// Fused GEMM + scan. r12 mechanisms on the r6 BNF=64 geometry for 4 blocks/CU:
//   - Pt (16 KB) ALIASES Asm (dead during epilogue/scan). LDS = 24 KB/block.
//     New barrier between last compute and Pt writes covers the alias.
//   - loadA(kt+1) issued AFTER the drain barrier (flies during compute;
//     consumed by next writeA via compiler-counted vmcnt).
//   - loadA(next tc, 0) issued before the serial scan (~3.5k cy cover).
//   - exp2-folded scan + nontemporal out stores (r12-proven).
__global__ __launch_bounds__(256, 4)
void fused_gemm_scan(const float* __restrict__ X, const u16* __restrict__ wt,
                     const float* __restrict__ bias, float* __restrict__ out) {
  __shared__ char L[24576];
  char* const Asm = L;              // 16 KB, [128 rows][64 k] bf16 swizzled
  char* const Bsm = L + 16384;      //  8 KB, [ 64 rows][64 k] bf16 swizzled
  char* const Pt  = L;              // 16 KB, [128 t][64 h] — ALIASES Asm

  const int tid  = threadIdx.x;
  const int lane = tid & 63;
  const int wave = tid >> 6;

  // XCD-aware decode (r6): the 16 h-tiles of one b land on the same XCD.
  const int rb  = blockIdx.x;           // 0..1023
  const int xcd = rb & 7;
  const int idx = rb >> 3;              // 0..127
  const int b   = xcd * 8 + (idx & 7);  // 0..63
  const int ht  = idx >> 3;             // 0..15
  const int n0  = ht * BNF;

  const int g  = lane >> 4;   // 0..3
  const int lr = lane & 15;
  const int wr = wave >> 1;   // 0..1 (m half: 64 rows)
  const int wc = wave & 1;    // 0..1 (n half: 32 cols)
  const int rSub = lane >> 3;                 // 0..7
  const int kec  = ((lane & 7) ^ rSub) * 8;   // B pre-swizzled src chunk

  // A staging thread mapping: 4 passes, row = p*32 + (tid>>3), chunk = tid&7
  const int arow = tid >> 3;   // 0..31
  const int ac   = tid & 7;    // 16B chunk within 128B row

  float bv[2];
  #pragma unroll
  for (int n = 0; n < 2; ++n)
    bv[n] = bias[n0 + wc*32 + n*16 + lr];

  const int hcol = tid;       // scanning thread's h (tid < 64 only)
  float hh = 0.f;             // recurrent state for this (b, h) chain

  f32x4 pre[8];               // A prefetch registers (static indices only)

  auto loadA = [&](int m0_, int k0) {
    #pragma unroll
    for (int p = 0; p < 4; ++p) {
      const float* s = X + (size_t)(m0_ + p*32 + arow) * K_ + k0 + ac*8;
      pre[2*p]   = *(const f32x4*)s;
      pre[2*p+1] = *(const f32x4*)(s + 4);
    }
  };
  auto writeA = [&]() {
    #pragma unroll
    for (int p = 0; p < 4; ++p) {
      const int row = p*32 + arow;
      s16x8 r;
      r[0]=f2bf(pre[2*p][0]);   r[1]=f2bf(pre[2*p][1]);
      r[2]=f2bf(pre[2*p][2]);   r[3]=f2bf(pre[2*p][3]);
      r[4]=f2bf(pre[2*p+1][0]); r[5]=f2bf(pre[2*p+1][1]);
      r[6]=f2bf(pre[2*p+1][2]); r[7]=f2bf(pre[2*p+1][3]);
      *(s16x8*)(Asm + row*128 + ((ac*16) ^ ((row & 7) << 4))) = r;
    }
  };
  auto stageB = [&](int k0) {
    #pragma unroll
    for (int p = 0; p < 2; ++p) {       // 8 slots of 8 rows
      const int slot = wave * 2 + p;
      const int r = slot * 8 + rSub;
      gload_lds16(wt + (size_t)(n0 + r) * K_ + k0 + kec, Bsm + slot * 1024);
    }
  };

  loadA(b * T_, 0);                     // initial A(0) prefetch

  #pragma unroll 1
  for (int tc = 0; tc < 4; ++tc) {
    const int m0 = b * T_ + tc * BM;

    f32x4 acc[4][2];
    #pragma unroll
    for (int m = 0; m < 4; ++m)
      #pragma unroll
      for (int n = 0; n < 2; ++n)
        acc[m][n] = (f32x4){0.f, 0.f, 0.f, 0.f};

    #pragma unroll 1
    for (int kt = 0; kt < NKT; ++kt) {
      if (kt) __syncthreads();          // readers done; drains prev A loads
      stageB(kt * BK);                  // async DMA into Bsm
      writeA();                         // consumes pre (compiler-counted wait)
      __syncthreads();                  // drains B DMAs + A ds_writes
      if (kt + 1 < NKT)
        loadA(m0, (kt + 1) * BK);       // flies during compute(kt)

      #pragma unroll
      for (int kk = 0; kk < BK; kk += 32) {
        s16x8 af[4], bf[2];
        #pragma unroll
        for (int m = 0; m < 4; ++m) {
          const int row = wr*64 + m*16 + lr;
          af[m] = *(const s16x8*)(Asm + row*128 +
                                  ((kk*2 + g*16) ^ ((row & 7) << 4)));
        }
        #pragma unroll
        for (int n = 0; n < 2; ++n) {
          const int row = wc*32 + n*16 + lr;
          bf[n] = *(const s16x8*)(Bsm + row*128 +
                                  ((kk*2 + g*16) ^ ((row & 7) << 4)));
        }
        #pragma unroll
        for (int m = 0; m < 4; ++m)
          #pragma unroll
          for (int n = 0; n < 2; ++n)
            acc[m][n] = __builtin_amdgcn_mfma_f32_16x16x32_bf16(
                af[m], bf[n], acc[m][n], 0, 0, 0);
      }
    }

    __syncthreads();    // ALIAS GUARD: all Asm/Bsm readers done before Pt writes

    // epilogue: pv = -relu(acc+bias)*log2e -> bf16 Pt (r6-proven swizzle
    // for the 128-B row: S(row) = ((row>>2)&3)<<5).
    #pragma unroll
    for (int m = 0; m < 4; ++m) {
      #pragma unroll
      for (int n = 0; n < 2; ++n) {
        const int col2 = (wc*32 + n*16 + lr) * 2;
        #pragma unroll
        for (int j = 0; j < 4; ++j) {
          const int row = wr*64 + m*16 + g*4 + j;
          const float pv = fmaxf(acc[m][n][j] + bv[n], 0.f) * (-L2E);
          *(u16*)(Pt + row*128 + (col2 ^ (((row>>2)&3) << 5))) = (u16)f2bf(pv);
        }
      }
    }
    __syncthreads();                    // Pt visible to scanners

    if (tc + 1 < 4) loadA(m0 + BM, 0);  // next tc's A(0) — hides under scan

    if (tid < 64) {
      float* o = out + (size_t)(b * T_ + tc * BM) * H_ + n0 + hcol;
      const int c2 = hcol * 2;
      #pragma unroll 8
      for (int t = 0; t < BM; ++t) {
        const float pv =
            bf2f(*(const u16*)(Pt + t*128 + (c2 ^ (((t>>2)&3) << 5))));
        // hh = sigmoid(hh + v) = 1/(1 + 2^fma(hh,-log2e,pv))
        hh = __builtin_amdgcn_rcpf(
            1.f + __builtin_amdgcn_exp2f(__builtin_fmaf(hh, -L2E, pv)));
        __builtin_nontemporal_store(hh, o + (size_t)t * H_);
      }
    }
    __syncthreads();                    // scan done before Asm(=Pt) overwrite
  }
}

// ---------------------------------------------------------------------------
// FALLBACK PATH (no workspace requirement)
// ---------------------------------------------------------------------------

__global__ __launch_bounds__(256, 2)
void gemm_bias_relu(const float* __restrict__ X, const float* __restrict__ W,
                    const float* __restrict__ bias, float* __restrict__ out) {
  __shared__ char Asm[BM*BK*2];
  __shared__ char Bsm[BN*BK*2];

  const int tid  = threadIdx.x;
  const int lane = tid & 63;
  const int wave = tid >> 6;
  const int m0 = blockIdx.x * BM;
  const int n0 = blockIdx.y * BN;

  const int arow  = tid >> 4;
  const int acol4 = (tid & 15) << 2;
  const int brow  = tid >> 5;
  const int bn4   = (tid & 31) << 2;

  const int g  = lane >> 4;
  const int lr = lane & 15;
  const int wr = wave >> 1;
  const int wc = wave & 1;

  s16x4 aRegs[8], bRegs[8];
  f32x4 acc[4][4];
  #pragma unroll
  for (int m = 0; m < 4; ++m)
    #pragma unroll
    for (int n = 0; n < 4; ++n)
      acc[m][n] = (f32x4){0.f, 0.f, 0.f, 0.f};

  auto loadTile = [&](int kt) {
    const int k0 = kt * BK;
    #pragma unroll
    for (int p = 0; p < 8; ++p) {
      const int r = p*16 + arow;
      f32x4 av = *(const f32x4*)(X + (size_t)(m0 + r)*K_ + k0 + acol4);
      aRegs[p] = cvt4(av);
      const int kk = p*8 + brow;
      f32x4 bv = *(const f32x4*)(W + (size_t)(k0 + kk)*N_ + n0 + bn4);
      bRegs[p] = cvt4(bv);
    }
  };
  auto writeTile = [&]() {
    #pragma unroll
    for (int p = 0; p < 8; ++p) {
      const int r = p*16 + arow;
      const int ao = ((r*BK + acol4) * 2) ^ ((r & 7) << 4);
      *(s16x4*)(Asm + ao) = aRegs[p];
      const int kk = p*8 + brow;
      #pragma unroll
      for (int i = 0; i < 4; ++i) {
        const int n = bn4 + i;
        const int bo = ((n*BK + kk) * 2) ^ ((n & 7) << 4);
        *(short*)(Bsm + bo) = bRegs[p][i];
      }
    }
  };
  auto mfmaTile = [&]() {
    #pragma unroll
    for (int kk = 0; kk < BK; kk += 32) {
      s16x8 af[4], bf[4];
      #pragma unroll
      for (int m = 0; m < 4; ++m) {
        const int r = wr*64 + m*16 + lr;
        af[m] = *(const s16x8*)(Asm + (((r*BK + kk + g*8) * 2) ^ ((r & 7) << 4)));
      }
      #pragma unroll
      for (int n = 0; n < 4; ++n) {
        const int c = wc*64 + n*16 + lr;
        bf[n] = *(const s16x8*)(Bsm + (((c*BK + kk + g*8) * 2) ^ ((c & 7) << 4)));
      }
      #pragma unroll
      for (int m = 0; m < 4; ++m)
        #pragma unroll
        for (int n = 0; n < 4; ++n)
          acc[m][n] = __builtin_amdgcn_mfma_f32_16x16x32_bf16(
              af[m], bf[n], acc[m][n], 0, 0, 0);
    }
  };

  loadTile(0);
  #pragma unroll 1
  for (int kt = 0; kt < NKT; ++kt) {
    if (kt) __syncthreads();
    writeTile();
    __syncthreads();
    if (kt + 1 < NKT) loadTile(kt + 1);
    mfmaTile();
  }

  float bv[4];
  #pragma unroll
  for (int n = 0; n < 4; ++n)
    bv[n] = bias[n0 + wc*64 + n*16 + lr];
  #pragma unroll
  for (int m = 0; m < 4; ++m)
    #pragma unroll
    for (int n = 0; n < 4; ++n) {
      const int col = n0 + wc*64 + n*16 + lr;
      #pragma unroll
      for (int j = 0; j < 4; ++j) {
        const int row = m0 + wr*64 + m*16 + g*4 + j;
        out[(size_t)row*N_ + col] = fmaxf(acc[m][n][j] + bv[n], 0.f);
      }
    }
}

#define PF 16
__global__ __launch_bounds__(256)
void scan_sigmoid(float* __restrict__ out) {
  const int tid = blockIdx.x * blockDim.x + threadIdx.x;
  const int b = tid >> 10;
  const int h = tid & (H_ - 1);
  float* p = out + (size_t)b * (T_ * H_) + h;

  float buf[PF];
  #pragma unroll
  for (int i = 0; i < PF; ++i) buf[i] = p[(size_t)i * H_];

  float hh = 0.f;
  #pragma unroll 1
  for (int t0 = 0; t0 < T_ - PF; t0 += PF) {
    #pragma unroll
    for (int i = 0; i < PF; ++i) {
      const float v = buf[i];
      buf[i] = p[(size_t)(t0 + i + PF) * H_];
      hh = __builtin_amdgcn_rcpf(1.f + __expf(-(hh + v)));
      p[(size_t)(t0 + i) * H_] = hh;
    }
  }
  #pragma unroll
  for (int i = 0; i < PF; ++i) {
    const float v = buf[i];
    hh = __builtin_amdgcn_rcpf(1.f + __expf(-(hh + v)));
    p[(size_t)(T_ - PF + i) * H_] = hh;
  }
}

// ---------------------------------------------------------------------------

extern "C" void kernel_launch(void* const* d_in, const int* in_sizes, int n_in,
                              void* d_out, int out_size, void* d_ws, size_t ws_size,
                              hipStream_t stream) {
  const float* x    = (const float*)d_in[0];
  const float* W    = (const float*)d_in[1];
  const float* bias = (const float*)d_in[2];
  float* out = (float*)d_out;

  const size_t WT = (size_t)N_ * K_ * 2;   // 1,048,576

  if (ws_size >= WT) {
    u16* wt = (u16*)d_ws;
    prep_w<<<128, 256, 0, stream>>>(W, wt);
    fused_gemm_scan<<<B_ * (N_/BNF), 256, 0, stream>>>(x, wt, bias, out);
  } else {
    gemm_bias_relu<<<dim3(M_/BM, N_/BN), 256, 0, stream>>>(x, W, bias, out);
    scan_sigmoid<<<(B_*H_)/256, 256, 0, stream>>>(out);
  }
}

// Round 14
// 77.938 us; speedup vs baseline: 1.1421x; 1.1421x over previous
//
#include <hip/hip_runtime.h>
#include <hip/hip_bf16.h>
#include <stdint.h>

// Problem constants
#define B_ 64
#define T_ 512
#define D_ 512
#define H_ 1024
#define M_ (B_*T_)   // 32768
#define K_ D_        // 512
#define N_ H_        // 1024

// Fused-kernel tile: 128 t-rows x 128 h-cols per block, BK=64 (r12-proven).
#define BM 128
#define BNF 128
#define BK 64
#define NKT (K_/BK)  // 8

// Fallback GEMM tile
#define BN 128

#define L2E 1.44269504f

typedef __attribute__((ext_vector_type(4))) float f32x4;
typedef __attribute__((ext_vector_type(8))) short s16x8;
typedef __attribute__((ext_vector_type(4))) short s16x4;
typedef unsigned short u16;

__device__ __forceinline__ short f2bf(float f) {
  __bf16 h = (__bf16)f;
  return __builtin_bit_cast(short, h);
}
__device__ __forceinline__ float bf2f(u16 u) {
  return __builtin_bit_cast(float, ((unsigned)u) << 16);
}
__device__ __forceinline__ s16x4 cvt4(f32x4 v) {
  s16x4 r;
  r[0] = f2bf(v[0]); r[1] = f2bf(v[1]);
  r[2] = f2bf(v[2]); r[3] = f2bf(v[3]);
  return r;
}
__device__ __forceinline__ void gload_lds16(const void* g, void* l) {
  __builtin_amdgcn_global_load_lds(
      (const __attribute__((address_space(1))) void*)g,
      (__attribute__((address_space(3))) void*)l, 16, 0, 0);
}

// ---------------------------------------------------------------------------
// FAST PATH (needs 1 MB workspace): prep_w (W transpose only) + fused
// ---------------------------------------------------------------------------

// W [K][N] fp32 -> wt [N][K] bf16 via 64x64 LDS tile transpose. 128 blocks.
__global__ __launch_bounds__(256)
void prep_w(const float* __restrict__ W, u16* __restrict__ wt) {
  __shared__ u16 Lt[64 * 72];   // 72-pad keeps 16B alignment of rows
  const int n0 = ((int)blockIdx.x & 15) * 64;
  const int k0 = ((int)blockIdx.x >> 4) * 64;
  const int tid = threadIdx.x;
  #pragma unroll
  for (int p = 0; p < 16; ++p) {
    const int idx = p * 256 + tid;
    const int r = idx >> 6;
    const int c = idx & 63;
    const float v = W[(size_t)(k0 + r) * H_ + n0 + c];
    Lt[c * 72 + r] = (u16)f2bf(v);
  }
  __syncthreads();
  #pragma unroll
  for (int p = 0; p < 2; ++p) {
    const int idx = p * 256 + tid;
    const int rn = idx >> 3;
    const int ck = (idx & 7) * 8;
    const s16x8 v = *(const s16x8*)&Lt[rn * 72 + ck];
    *(s16x8*)&wt[(size_t)(n0 + rn) * K_ + k0 + ck] = v;
  }
}

// Fused GEMM + scan — r12 (best passing, 78.1) + r3-proven tc-transition
// overlap: the NEXT tc's kt=0 staging (B DMAs + A register loads) is issued
// BEFORE the serial scan, so its latency hides under the scan instead of
// being exposed at the next tc's first drain barrier. stageB(kt=0) is hoisted
// out of the kt loop; kt>=1 staging, swizzles, epilogue, scan are byte-
// identical to r12. Scan-end barrier KEPT (conservative).
__global__ __launch_bounds__(256, 2)
void fused_gemm_scan(const float* __restrict__ X, const u16* __restrict__ wt,
                     const float* __restrict__ bias, float* __restrict__ out) {
  __shared__ char Asm[BM * BK * 2];     // 16 KB, [128 rows][64 k] bf16
  __shared__ char Bsm[BNF * BK * 2];    // 16 KB, [128 rows][64 k] bf16
  __shared__ char Pt[BM * BNF * 2];     // 32 KB, [128 t][128 h] bf16 swizzled

  const int tid  = threadIdx.x;
  const int lane = tid & 63;
  const int wave = tid >> 6;

  // XCD-aware decode: the 8 h-tiles of one b land on the same XCD so that
  // b's 1 MB fp32 A-panel is fetched once into that XCD's L2.
  const int rb  = blockIdx.x;           // 0..511
  const int xcd = rb & 7;
  const int idx = rb >> 3;              // 0..63
  const int b   = xcd * 8 + (idx & 7);  // 0..63
  const int ht  = idx >> 3;             // 0..7
  const int n0  = ht * BNF;

  const int g  = lane >> 4;   // 0..3
  const int lr = lane & 15;
  const int wr = wave >> 1;   // 0..1 (m half)
  const int wc = wave & 1;    // 0..1 (n half)
  const int rSub = lane >> 3;                 // 0..7 (= staged row & 7)
  const int kec  = ((lane & 7) ^ rSub) * 8;   // B pre-swizzled src chunk

  // A staging thread mapping: 4 passes, row = p*32 + (tid>>3), chunk = tid&7
  const int arow = tid >> 3;   // 0..31
  const int ac   = tid & 7;    // 16B chunk within 128B row

  float bv[4];
  #pragma unroll
  for (int n = 0; n < 4; ++n)
    bv[n] = bias[n0 + wc*64 + n*16 + lr];

  const int hcol = tid;       // scanning thread's h (tid < 128 only)
  float hh = 0.f;             // recurrent state for this (b, h) chain

  f32x4 pre[8];               // A prefetch registers (static indices only)

  auto loadA = [&](int m0_, int k0) {
    #pragma unroll
    for (int p = 0; p < 4; ++p) {
      const float* s = X + (size_t)(m0_ + p*32 + arow) * K_ + k0 + ac*8;
      pre[2*p]   = *(const f32x4*)s;
      pre[2*p+1] = *(const f32x4*)(s + 4);
    }
  };
  auto writeA = [&]() {
    #pragma unroll
    for (int p = 0; p < 4; ++p) {
      const int row = p*32 + arow;
      s16x8 r;
      r[0]=f2bf(pre[2*p][0]);   r[1]=f2bf(pre[2*p][1]);
      r[2]=f2bf(pre[2*p][2]);   r[3]=f2bf(pre[2*p][3]);
      r[4]=f2bf(pre[2*p+1][0]); r[5]=f2bf(pre[2*p+1][1]);
      r[6]=f2bf(pre[2*p+1][2]); r[7]=f2bf(pre[2*p+1][3]);
      *(s16x8*)(Asm + row*128 + ((ac*16) ^ ((row & 7) << 4))) = r;
    }
  };
  auto stageB = [&](int k0) {
    #pragma unroll
    for (int p = 0; p < 4; ++p) {       // 16 slots of 8 rows
      const int slot = wave * 4 + p;
      const int r = slot * 8 + rSub;
      gload_lds16(wt + (size_t)(n0 + r) * K_ + k0 + kec, Bsm + slot * 1024);
    }
  };

  // prologue: A(tc=0,kt=0) regs + B(tc=0,kt=0) DMAs in flight
  loadA(b * T_, 0);
  stageB(0);

  #pragma unroll 1
  for (int tc = 0; tc < 4; ++tc) {
    const int m0 = b * T_ + tc * BM;

    f32x4 acc[4][4];
    #pragma unroll
    for (int m = 0; m < 4; ++m)
      #pragma unroll
      for (int n = 0; n < 4; ++n)
        acc[m][n] = (f32x4){0.f, 0.f, 0.f, 0.f};

    #pragma unroll 1
    for (int kt = 0; kt < NKT; ++kt) {
      // kt=0: B DMAs already in flight (issued pre-scan / prologue).
      if (kt) {
        __syncthreads();                // prev kt's frag reads done
        stageB(kt * BK);                // async DMA into Bsm
      }
      writeA();                         // cvt + swizzled ds_write into Asm
      if (kt + 1 < NKT)
        loadA(m0, (kt + 1) * BK);       // issue next A loads (regs) NOW
      __syncthreads();                  // drains vmcnt (B) + lgkm (A writes)

      #pragma unroll
      for (int kk = 0; kk < BK; kk += 32) {
        s16x8 af[4], bf[4];
        #pragma unroll
        for (int m = 0; m < 4; ++m) {
          const int row = wr*64 + m*16 + lr;
          af[m] = *(const s16x8*)(Asm + row*128 +
                                  ((kk*2 + g*16) ^ ((row & 7) << 4)));
        }
        #pragma unroll
        for (int n = 0; n < 4; ++n) {
          const int row = wc*64 + n*16 + lr;
          bf[n] = *(const s16x8*)(Bsm + row*128 +
                                  ((kk*2 + g*16) ^ ((row & 7) << 4)));
        }
        #pragma unroll
        for (int m = 0; m < 4; ++m)
          #pragma unroll
          for (int n = 0; n < 4; ++n)
            acc[m][n] = __builtin_amdgcn_mfma_f32_16x16x32_bf16(
                af[m], bf[n], acc[m][n], 0, 0, 0);
      }
    }

    // epilogue: pv = -relu(acc+bias)*log2e -> bf16 Pt (r3-proven swizzle).
    #pragma unroll
    for (int m = 0; m < 4; ++m) {
      #pragma unroll
      for (int n = 0; n < 4; ++n) {
        const int col2 = (wc*64 + n*16 + lr) * 2;
        #pragma unroll
        for (int j = 0; j < 4; ++j) {
          const int row = wr*64 + m*16 + g*4 + j;
          const float pv = fmaxf(acc[m][n][j] + bv[n], 0.f) * (-L2E);
          *(u16*)(Pt + row*256 + (col2 ^ (((row>>2)&7) << 5))) = (u16)f2bf(pv);
        }
      }
    }
    __syncthreads();                    // Pt visible; all Asm/Bsm reads done

    // tc-transition overlap (r3-proven): issue NEXT tc's kt=0 staging now —
    // B DMAs land in Bsm (idle during scan; Pt is separate), A loads fly.
    // Their latency hides under the serial scan below.
    if (tc + 1 < 4) {
      loadA(m0 + BM, 0);
      stageB(0);
    }

    if (tid < 128) {
      float* o = out + (size_t)(b * T_ + tc * BM) * H_ + n0 + hcol;
      const int c2 = hcol * 2;
      #pragma unroll 8
      for (int t = 0; t < BM; ++t) {
        const float pv =
            bf2f(*(const u16*)(Pt + t*256 + (c2 ^ (((t>>2)&7) << 5))));
        // hh = sigmoid(hh + v) = 1/(1 + 2^fma(hh,-log2e,pv))
        hh = __builtin_amdgcn_rcpf(
            1.f + __builtin_amdgcn_exp2f(__builtin_fmaf(hh, -L2E, pv)));
        __builtin_nontemporal_store(hh, o + (size_t)t * H_);
      }
    }
    __syncthreads();                    // scan done before LDS overwrite
  }
}

// ---------------------------------------------------------------------------
// FALLBACK PATH (no workspace requirement)
// ---------------------------------------------------------------------------

__global__ __launch_bounds__(256, 2)
void gemm_bias_relu(const float* __restrict__ X, const float* __restrict__ W,
                    const float* __restrict__ bias, float* __restrict__ out) {
  __shared__ char Asm[BM*BK*2];
  __shared__ char Bsm[BN*BK*2];

  const int tid  = threadIdx.x;
  const int lane = tid & 63;
  const int wave = tid >> 6;
  const int m0 = blockIdx.x * BM;
  const int n0 = blockIdx.y * BN;

  const int arow  = tid >> 4;
  const int acol4 = (tid & 15) << 2;
  const int brow  = tid >> 5;
  const int bn4   = (tid & 31) << 2;

  const int g  = lane >> 4;
  const int lr = lane & 15;
  const int wr = wave >> 1;
  const int wc = wave & 1;

  s16x4 aRegs[8], bRegs[8];
  f32x4 acc[4][4];
  #pragma unroll
  for (int m = 0; m < 4; ++m)
    #pragma unroll
    for (int n = 0; n < 4; ++n)
      acc[m][n] = (f32x4){0.f, 0.f, 0.f, 0.f};

  auto loadTile = [&](int kt) {
    const int k0 = kt * BK;
    #pragma unroll
    for (int p = 0; p < 8; ++p) {
      const int r = p*16 + arow;
      f32x4 av = *(const f32x4*)(X + (size_t)(m0 + r)*K_ + k0 + acol4);
      aRegs[p] = cvt4(av);
      const int kk = p*8 + brow;
      f32x4 bv = *(const f32x4*)(W + (size_t)(k0 + kk)*N_ + n0 + bn4);
      bRegs[p] = cvt4(bv);
    }
  };
  auto writeTile = [&]() {
    #pragma unroll
    for (int p = 0; p < 8; ++p) {
      const int r = p*16 + arow;
      const int ao = ((r*BK + acol4) * 2) ^ ((r & 7) << 4);
      *(s16x4*)(Asm + ao) = aRegs[p];
      const int kk = p*8 + brow;
      #pragma unroll
      for (int i = 0; i < 4; ++i) {
        const int n = bn4 + i;
        const int bo = ((n*BK + kk) * 2) ^ ((n & 7) << 4);
        *(short*)(Bsm + bo) = bRegs[p][i];
      }
    }
  };
  auto mfmaTile = [&]() {
    #pragma unroll
    for (int kk = 0; kk < BK; kk += 32) {
      s16x8 af[4], bf[4];
      #pragma unroll
      for (int m = 0; m < 4; ++m) {
        const int r = wr*64 + m*16 + lr;
        af[m] = *(const s16x8*)(Asm + (((r*BK + kk + g*8) * 2) ^ ((r & 7) << 4)));
      }
      #pragma unroll
      for (int n = 0; n < 4; ++n) {
        const int c = wc*64 + n*16 + lr;
        bf[n] = *(const s16x8*)(Bsm + (((c*BK + kk + g*8) * 2) ^ ((c & 7) << 4)));
      }
      #pragma unroll
      for (int m = 0; m < 4; ++m)
        #pragma unroll
        for (int n = 0; n < 4; ++n)
          acc[m][n] = __builtin_amdgcn_mfma_f32_16x16x32_bf16(
              af[m], bf[n], acc[m][n], 0, 0, 0);
    }
  };

  loadTile(0);
  #pragma unroll 1
  for (int kt = 0; kt < NKT; ++kt) {
    if (kt) __syncthreads();
    writeTile();
    __syncthreads();
    if (kt + 1 < NKT) loadTile(kt + 1);
    mfmaTile();
  }

  float bv[4];
  #pragma unroll
  for (int n = 0; n < 4; ++n)
    bv[n] = bias[n0 + wc*64 + n*16 + lr];
  #pragma unroll
  for (int m = 0; m < 4; ++m)
    #pragma unroll
    for (int n = 0; n < 4; ++n) {
      const int col = n0 + wc*64 + n*16 + lr;
      #pragma unroll
      for (int j = 0; j < 4; ++j) {
        const int row = m0 + wr*64 + m*16 + g*4 + j;
        out[(size_t)row*N_ + col] = fmaxf(acc[m][n][j] + bv[n], 0.f);
      }
    }
}

#define PF 16
__global__ __launch_bounds__(256)
void scan_sigmoid(float* __restrict__ out) {
  const int tid = blockIdx.x * blockDim.x + threadIdx.x;
  const int b = tid >> 10;
  const int h = tid & (H_ - 1);
  float* p = out + (size_t)b * (T_ * H_) + h;

  float buf[PF];
  #pragma unroll
  for (int i = 0; i < PF; ++i) buf[i] = p[(size_t)i * H_];

  float hh = 0.f;
  #pragma unroll 1
  for (int t0 = 0; t0 < T_ - PF; t0 += PF) {
    #pragma unroll
    for (int i = 0; i < PF; ++i) {
      const float v = buf[i];
      buf[i] = p[(size_t)(t0 + i + PF) * H_];
      hh = __builtin_amdgcn_rcpf(1.f + __expf(-(hh + v)));
      p[(size_t)(t0 + i) * H_] = hh;
    }
  }
  #pragma unroll
  for (int i = 0; i < PF; ++i) {
    const float v = buf[i];
    hh = __builtin_amdgcn_rcpf(1.f + __expf(-(hh + v)));
    p[(size_t)(T_ - PF + i) * H_] = hh;
  }
}

// ---------------------------------------------------------------------------

extern "C" void kernel_launch(void* const* d_in, const int* in_sizes, int n_in,
                              void* d_out, int out_size, void* d_ws, size_t ws_size,
                              hipStream_t stream) {
  const float* x    = (const float*)d_in[0];
  const float* W    = (const float*)d_in[1];
  const float* bias = (const float*)d_in[2];
  float* out = (float*)d_out;

  const size_t WT = (size_t)N_ * K_ * 2;   // 1,048,576

  if (ws_size >= WT) {
    u16* wt = (u16*)d_ws;
    prep_w<<<128, 256, 0, stream>>>(W, wt);
    fused_gemm_scan<<<B_ * (N_/BNF), 256, 0, stream>>>(x, wt, bias, out);
  } else {
    gemm_bias_relu<<<dim3(M_/BM, N_/BN), 256, 0, stream>>>(x, W, bias, out);
    scan_sigmoid<<<(B_*H_)/256, 256, 0, stream>>>(out);
  }
}